// Round 1
// baseline (560.805 us; speedup 1.0000x reference)
//
#include <hip/hip_runtime.h>
#include <hip/hip_bf16.h>
#include <stdint.h>

typedef unsigned short u16;
typedef __attribute__((ext_vector_type(4))) unsigned int u32x4;
typedef __attribute__((ext_vector_type(8))) __bf16 bfx8;
typedef __attribute__((ext_vector_type(4))) float f32x4;

#define PI_F 3.14159265358979323846f

__device__ __forceinline__ float bf2f(u16 u) {
    unsigned v = ((unsigned)u) << 16; float f; __builtin_memcpy(&f, &v, 4); return f;
}
__device__ __forceinline__ u16 f2bf(float f) {
    unsigned u; __builtin_memcpy(&u, &f, 4);
    unsigned r = (u + 0x7fffu + ((u >> 16) & 1u)) >> 16; return (u16)r;
}

// ---------------------------------------------------------------------------
// Generic tiled transpose + f32->bf16 convert:  out[c][r] = in[r][c], batched.
// grid: (ceil(C/64), ceil(R/64), batch), block 256.
// ---------------------------------------------------------------------------
__global__ __launch_bounds__(256)
void tconv_kernel(const float* __restrict__ in, u16* __restrict__ out,
                  int R, int C, long inBatch, long outBatch)
{
    __shared__ float tile[64][65];
    const int tx = threadIdx.x & 63;
    const int ty = threadIdx.x >> 6;
    const int bc = blockIdx.x * 64;
    const int br = blockIdx.y * 64;
    const float* ip = in + (long)blockIdx.z * inBatch;
    u16* op = out + (long)blockIdx.z * outBatch;

    #pragma unroll
    for (int rr = ty; rr < 64; rr += 4) {
        int r = br + rr, c = bc + tx;
        tile[rr][tx] = (r < R && c < C) ? ip[(long)r * C + c] : 0.f;
    }
    __syncthreads();
    #pragma unroll
    for (int rr = ty; rr < 64; rr += 4) {
        int oc = bc + rr;      // output row index (original col)
        int orr = br + tx;     // output col index (original row)
        if (oc < C && orr < R)
            op[(long)oc * R + orr] = f2bf(tile[tx][rr]);
    }
}

// ---------------------------------------------------------------------------
// LayerNorm (+ optional rank-1 q/k projections + tanh/cos/sin).
// One block (256 thr) per row of 1024.
// ---------------------------------------------------------------------------
template<bool DO_QK>
__global__ __launch_bounds__(256)
void ln_kernel(const float* __restrict__ X, const float* __restrict__ w,
               const float* __restrict__ b, u16* __restrict__ Ybf,
               const float* __restrict__ WQ, const float* __restrict__ WK,
               float* __restrict__ cqA, float* __restrict__ sqA,
               float* __restrict__ ckA, float* __restrict__ skA)
{
    __shared__ float yrow[1024];
    __shared__ float wsum[4], wsq[4];
    const int row = blockIdx.x;
    const int tid = threadIdx.x;
    const int lane = tid & 63;
    const int wv = tid >> 6;

    const float4 xv = ((const float4*)(X + (long)row * 1024))[tid];
    float s  = xv.x + xv.y + xv.z + xv.w;
    float sq = xv.x*xv.x + xv.y*xv.y + xv.z*xv.z + xv.w*xv.w;
    #pragma unroll
    for (int off = 32; off; off >>= 1) {
        s  += __shfl_down(s, off);
        sq += __shfl_down(sq, off);
    }
    if (lane == 0) { wsum[wv] = s; wsq[wv] = sq; }
    __syncthreads();
    const float ts = wsum[0] + wsum[1] + wsum[2] + wsum[3];
    const float tq = wsq[0] + wsq[1] + wsq[2] + wsq[3];
    const float mean = ts * (1.f / 1024.f);
    const float var  = tq * (1.f / 1024.f) - mean * mean;
    const float rstd = rsqrtf(var + 1e-5f);

    const float4 wv4 = ((const float4*)w)[tid];
    const float4 bv4 = ((const float4*)b)[tid];
    const float y0 = (xv.x - mean) * rstd * wv4.x + bv4.x;
    const float y1 = (xv.y - mean) * rstd * wv4.y + bv4.y;
    const float y2 = (xv.z - mean) * rstd * wv4.z + bv4.z;
    const float y3 = (xv.w - mean) * rstd * wv4.w + bv4.w;

    uint2 p;
    p.x = (unsigned)f2bf(y0) | ((unsigned)f2bf(y1) << 16);
    p.y = (unsigned)f2bf(y2) | ((unsigned)f2bf(y3) << 16);
    ((uint2*)(Ybf + (long)row * 1024))[tid] = p;

    if (DO_QK) {
        yrow[tid*4+0] = y0; yrow[tid*4+1] = y1;
        yrow[tid*4+2] = y2; yrow[tid*4+3] = y3;
        __syncthreads();
        #pragma unroll
        for (int i = 0; i < 4; ++i) {
            const int h = wv * 4 + i;
            const float* wqp = WQ + (long)h * 1024;
            const float* wkp = WK + (long)h * 1024;
            float dq = 0.f, dk = 0.f;
            #pragma unroll
            for (int j = 0; j < 16; ++j) {
                const float yv = yrow[lane + 64*j];
                dq = fmaf(yv, wqp[lane + 64*j], dq);
                dk = fmaf(yv, wkp[lane + 64*j], dk);
            }
            #pragma unroll
            for (int off = 32; off; off >>= 1) {
                dq += __shfl_down(dq, off);
                dk += __shfl_down(dk, off);
            }
            if (lane == 0) {
                const float aq = tanhf(dq) * (PI_F * 0.25f);
                const float ak = tanhf(dk) * (PI_F * 0.25f);
                float sv, cv;
                const long o = (long)h * 8192 + row;
                __sincosf(aq, &sv, &cv); cqA[o] = cv; sqA[o] = sv;
                __sincosf(ak, &sv, &cv); ckA[o] = cv; skA[o] = sv;
            }
        }
    }
}

// ---------------------------------------------------------------------------
// Fused cumsum scan + heads:  one wave per (b, head).
// heads[t][c] = (cq*cumsum(ck*V) + sq*cumsum(sk*V)) / (cq*cumsum(ck)+sq*cumsum(sk)+eps)
// ---------------------------------------------------------------------------
__global__ __launch_bounds__(64)
void scan_kernel(const u16* __restrict__ V,
                 const float* __restrict__ cqA, const float* __restrict__ sqA,
                 const float* __restrict__ ckA, const float* __restrict__ skA,
                 u16* __restrict__ H)
{
    __shared__ u16 vt[64][64];
    __shared__ float lck[64], lsk[64], lrc[64], lrs[64];
    const int b = blockIdx.x >> 4;
    const int h = blockIdx.x & 15;
    const int lane = threadIdx.x;
    const long rowbase = (long)b * 2048;
    const long colbase = (long)h * 64;
    const long qbase = (long)h * 8192 + rowbase;

    float csum = 0.f, ssum = 0.f;
    float carry_c = 0.f, carry_s = 0.f;

    for (int ch = 0; ch < 32; ++ch) {
        const int t0 = ch * 64;
        __syncthreads();   // prev serial reads of vt/l* done
        // load 64x64 bf16 V tile (coalesced: 8 lanes x 16B per row)
        #pragma unroll
        for (int i = 0; i < 8; ++i) {
            const int tt = i * 8 + (lane >> 3);
            const int c0 = (lane & 7) * 8;
            *(u32x4*)&vt[tt][c0] =
                *(const u32x4*)(V + (rowbase + t0 + tt) * 1024 + colbase + c0);
        }
        // per-head denominator scan (lane = t within chunk)
        {
            const float ck = ckA[qbase + t0 + lane];
            const float sk = skA[qbase + t0 + lane];
            const float cq = cqA[qbase + t0 + lane];
            const float sq = sqA[qbase + t0 + lane];
            float c = ck, sscan = sk;
            #pragma unroll
            for (int off = 1; off < 64; off <<= 1) {
                const float oc = __shfl_up(c, off);
                const float os = __shfl_up(sscan, off);
                if (lane >= off) { c += oc; sscan += os; }
            }
            const float cK = carry_c + c;
            const float sK = carry_s + sscan;
            carry_c += __shfl(c, 63);
            carry_s += __shfl(sscan, 63);
            const float denom = cq * cK + sq * sK + 1e-6f;
            lck[lane] = ck; lsk[lane] = sk;
            lrc[lane] = cq / denom; lrs[lane] = sq / denom;
        }
        __syncthreads();
        u16* outp = H + (rowbase + t0) * 1024 + colbase + lane;
        #pragma unroll 8
        for (int tt = 0; tt < 64; ++tt) {
            const float v = bf2f(vt[tt][lane]);
            csum = fmaf(lck[tt], v, csum);
            ssum = fmaf(lsk[tt], v, ssum);
            const float hv = lrc[tt] * csum + lrs[tt] * ssum;
            outp[(long)tt * 1024] = f2bf(hv);
        }
    }
}

// ---------------------------------------------------------------------------
// bf16 MFMA GEMM:  C[M][N] = A[M][K] * B^T  (Bt stored [N][K]).
// 128x128 tile, BK=32, 4 waves (2x2), 4x4 16x16x32 fragments per wave.
// EPI: 0 = bf16 store; 1 = f32 store + res; 2 = bf16 gelu(acc+bias);
//      3 = f32 store + res + bias.
// ---------------------------------------------------------------------------
template<int EPI>
__global__ __launch_bounds__(256, 2)
void gemm_bt(const u16* __restrict__ A, const u16* __restrict__ B,
             void* __restrict__ Cout, const float* __restrict__ res,
             const float* __restrict__ bias, int M, int N, int K)
{
    __shared__ u16 As[128 * 32];
    __shared__ u16 Bs[128 * 32];
    const int tid  = threadIdx.x;
    const int lane = tid & 63;
    const int wave = tid >> 6;
    const int wr = wave >> 1;
    const int wc = wave & 1;
    const int brow = blockIdx.y * 128;
    const int bcol = blockIdx.x * 128;

    const int srow = tid >> 2;           // 0..63
    const int scol = (tid & 3) * 8;      // bf16 elems within 32-wide k
    const u16* Ag = A + (long)(brow + srow) * K + scol;
    const u16* Bg = B + (long)(bcol + srow) * K + scol;

    f32x4 acc[4][4];
    #pragma unroll
    for (int i = 0; i < 4; ++i)
        #pragma unroll
        for (int j = 0; j < 4; ++j) acc[i][j] = (f32x4){0.f, 0.f, 0.f, 0.f};

    const int KT = K >> 5;
    u32x4 ar0 = *(const u32x4*)(Ag);
    u32x4 ar1 = *(const u32x4*)(Ag + (long)64 * K);
    u32x4 br0 = *(const u32x4*)(Bg);
    u32x4 br1 = *(const u32x4*)(Bg + (long)64 * K);

    const int kgrp = (lane >> 4) * 8;
    const int rr = lane & 15;

    for (int kt = 0; kt < KT; ++kt) {
        __syncthreads();
        *(u32x4*)&As[srow * 32 + scol]        = ar0;
        *(u32x4*)&As[(srow + 64) * 32 + scol] = ar1;
        *(u32x4*)&Bs[srow * 32 + scol]        = br0;
        *(u32x4*)&Bs[(srow + 64) * 32 + scol] = br1;
        __syncthreads();
        if (kt + 1 < KT) {
            const u16* Ag2 = Ag + (kt + 1) * 32;
            const u16* Bg2 = Bg + (kt + 1) * 32;
            ar0 = *(const u32x4*)(Ag2);
            ar1 = *(const u32x4*)(Ag2 + (long)64 * K);
            br0 = *(const u32x4*)(Bg2);
            br1 = *(const u32x4*)(Bg2 + (long)64 * K);
        }
        bfx8 af[4], bfr[4];
        #pragma unroll
        for (int m = 0; m < 4; ++m)
            af[m] = *(const bfx8*)&As[(wr * 64 + m * 16 + rr) * 32 + kgrp];
        #pragma unroll
        for (int n = 0; n < 4; ++n)
            bfr[n] = *(const bfx8*)&Bs[(wc * 64 + n * 16 + rr) * 32 + kgrp];
        #pragma unroll
        for (int m = 0; m < 4; ++m)
            #pragma unroll
            for (int n = 0; n < 4; ++n)
                acc[m][n] = __builtin_amdgcn_mfma_f32_16x16x32_bf16(
                    af[m], bfr[n], acc[m][n], 0, 0, 0);
    }

    const int crow0 = brow + wr * 64 + (lane >> 4) * 4;
    const int ccol0 = bcol + wc * 64 + (lane & 15);
    #pragma unroll
    for (int m = 0; m < 4; ++m) {
        #pragma unroll
        for (int n = 0; n < 4; ++n) {
            const int col = ccol0 + n * 16;
            #pragma unroll
            for (int r = 0; r < 4; ++r) {
                const int row = crow0 + m * 16 + r;
                const long idx = (long)row * N + col;
                const float v = acc[m][n][r];
                if (EPI == 0) {
                    ((u16*)Cout)[idx] = f2bf(v);
                } else if (EPI == 1) {
                    ((float*)Cout)[idx] = v + res[idx];
                } else if (EPI == 2) {
                    const float hh = v + bias[col];
                    const float g = 0.5f * hh *
                        (1.f + tanhf(0.7978845608028654f * (hh + 0.044715f * hh * hh * hh)));
                    ((u16*)Cout)[idx] = f2bf(g);
                } else {
                    ((float*)Cout)[idx] = v + res[idx] + bias[col];
                }
            }
        }
    }
}

// ---------------------------------------------------------------------------
extern "C" void kernel_launch(void* const* d_in, const int* in_sizes, int n_in,
                              void* d_out, int out_size, void* d_ws, size_t ws_size,
                              hipStream_t stream)
{
    (void)in_sizes; (void)n_in; (void)out_size; (void)ws_size;
    const float* x    = (const float*)d_in[0];
    const float* WQ   = (const float*)d_in[1];
    const float* WK   = (const float*)d_in[2];
    const float* WV   = (const float*)d_in[3];
    const float* WO   = (const float*)d_in[4];
    const float* ln1w = (const float*)d_in[5];
    const float* ln1b = (const float*)d_in[6];
    const float* ln2w = (const float*)d_in[7];
    const float* ln2b = (const float*)d_in[8];
    const float* W1   = (const float*)d_in[9];
    const float* b1   = (const float*)d_in[10];
    const float* W2   = (const float*)d_in[11];
    const float* b2   = (const float*)d_in[12];
    float* out = (float*)d_out;

    char* ws = (char*)d_ws;
    u16*   Ybf  = (u16*)(ws + 0);                    // 16,777,216  (reused as y2)
    u16*   Vbf  = (u16*)(ws + 16777216);             // 16,777,216
    u16*   Hbf  = (u16*)(ws + 33554432);             // 16,777,216
    float* X2   = (float*)(ws + 50331648);           // 33,554,432
    u16*   H1   = (u16*)(ws + 83886080);             // 67,108,864
    u16*   WVT  = (u16*)(ws + 150994944);            //  2,097,152
    u16*   WOT  = (u16*)(ws + 153092096);            //  2,097,152
    u16*   W1T  = (u16*)(ws + 155189248);            //  8,388,608
    u16*   W2T  = (u16*)(ws + 163577856);            //  8,388,608
    float* CQ   = (float*)(ws + 171966464);
    float* SQ   = (float*)(ws + 172490752);
    float* CK   = (float*)(ws + 173015040);
    float* SK   = (float*)(ws + 173539328);

    // weight transposes/converts to Bt[n][k] bf16
    tconv_kernel<<<dim3(1, 16, 16), 256, 0, stream>>>(WV, WVT, 1024, 64, 1024L*64, 64L*1024);
    tconv_kernel<<<dim3(1, 1, 1024), 256, 0, stream>>>(WO, WOT, 64, 16, 1024L, 1024L);
    tconv_kernel<<<dim3(64, 16, 1), 256, 0, stream>>>(W1, W1T, 1024, 4096, 0L, 0L);
    tconv_kernel<<<dim3(16, 64, 1), 256, 0, stream>>>(W2, W2T, 4096, 1024, 0L, 0L);

    // LN1 + q/k rank-1 projections + tanh/cos/sin
    ln_kernel<true><<<8192, 256, 0, stream>>>(x, ln1w, ln1b, Ybf, WQ, WK, CQ, SQ, CK, SK);

    // V = y @ Wv   (M=8192, N=1024, K=1024) -> bf16
    gemm_bt<0><<<dim3(8, 64), 256, 0, stream>>>(Ybf, WVT, Vbf, nullptr, nullptr, 8192, 1024, 1024);

    // cumsum scan + heads
    scan_kernel<<<64, 64, 0, stream>>>(Vbf, CQ, SQ, CK, SK, Hbf);

    // x2 = x + heads @ Wo   (M=8192, N=1024, K=1024) -> f32
    gemm_bt<1><<<dim3(8, 64), 256, 0, stream>>>(Hbf, WOT, X2, x, nullptr, 8192, 1024, 1024);

    // LN2 (y2 reuses Ybf)
    ln_kernel<false><<<8192, 256, 0, stream>>>(X2, ln2w, ln2b, Ybf,
                                               nullptr, nullptr, nullptr, nullptr, nullptr, nullptr);

    // h1 = gelu(y2 @ W1 + b1)  (M=8192, N=4096, K=1024) -> bf16
    gemm_bt<2><<<dim3(32, 64), 256, 0, stream>>>(Ybf, W1T, H1, nullptr, b1, 8192, 4096, 1024);

    // out = x2 + h1 @ W2 + b2  (M=8192, N=1024, K=4096) -> f32
    gemm_bt<3><<<dim3(8, 64), 256, 0, stream>>>(H1, W2T, out, X2, b2, 8192, 1024, 4096);
}

// Round 2
// 559.432 us; speedup vs baseline: 1.0025x; 1.0025x over previous
//
#include <hip/hip_runtime.h>
#include <hip/hip_bf16.h>
#include <stdint.h>

typedef unsigned short u16;
typedef __attribute__((ext_vector_type(4))) unsigned int u32x4;
typedef __attribute__((ext_vector_type(8))) __bf16 bfx8;
typedef __attribute__((ext_vector_type(4))) float f32x4;

#define PI_F 3.14159265358979323846f

__device__ __forceinline__ float bf2f(u16 u) {
    unsigned v = ((unsigned)u) << 16; float f; __builtin_memcpy(&f, &v, 4); return f;
}
__device__ __forceinline__ u16 f2bf(float f) {
    unsigned u; __builtin_memcpy(&u, &f, 4);
    unsigned r = (u + 0x7fffu + ((u >> 16) & 1u)) >> 16; return (u16)r;
}

// global -> LDS direct DMA, 16B per lane. LDS dest must be lane-linear.
__device__ __forceinline__ void glds16(const u16* g, const u16* l) {
    __builtin_amdgcn_global_load_lds(
        (const __attribute__((address_space(1))) unsigned int*)(unsigned long long)g,
        (__attribute__((address_space(3))) unsigned int*)(unsigned int)(unsigned long long)l,
        16, 0, 0);
}

// ---------------------------------------------------------------------------
// Generic tiled transpose + f32->bf16 convert:  out[c][r] = in[r][c], batched.
// ---------------------------------------------------------------------------
__global__ __launch_bounds__(256)
void tconv_kernel(const float* __restrict__ in, u16* __restrict__ out,
                  int R, int C, long inBatch, long outBatch)
{
    __shared__ float tile[64][65];
    const int tx = threadIdx.x & 63;
    const int ty = threadIdx.x >> 6;
    const int bc = blockIdx.x * 64;
    const int br = blockIdx.y * 64;
    const float* ip = in + (long)blockIdx.z * inBatch;
    u16* op = out + (long)blockIdx.z * outBatch;

    #pragma unroll
    for (int rr = ty; rr < 64; rr += 4) {
        int r = br + rr, c = bc + tx;
        tile[rr][tx] = (r < R && c < C) ? ip[(long)r * C + c] : 0.f;
    }
    __syncthreads();
    #pragma unroll
    for (int rr = ty; rr < 64; rr += 4) {
        int oc = bc + rr;
        int orr = br + tx;
        if (oc < C && orr < R)
            op[(long)oc * R + orr] = f2bf(tile[tx][rr]);
    }
}

// ---------------------------------------------------------------------------
// LayerNorm (+ optional rank-1 q/k projections + tanh/cos/sin).
// ---------------------------------------------------------------------------
template<bool DO_QK>
__global__ __launch_bounds__(256)
void ln_kernel(const float* __restrict__ X, const float* __restrict__ w,
               const float* __restrict__ b, u16* __restrict__ Ybf,
               const float* __restrict__ WQ, const float* __restrict__ WK,
               float* __restrict__ cqA, float* __restrict__ sqA,
               float* __restrict__ ckA, float* __restrict__ skA)
{
    __shared__ float yrow[1024];
    __shared__ float wsum[4], wsq[4];
    const int row = blockIdx.x;
    const int tid = threadIdx.x;
    const int lane = tid & 63;
    const int wv = tid >> 6;

    const float4 xv = ((const float4*)(X + (long)row * 1024))[tid];
    float s  = xv.x + xv.y + xv.z + xv.w;
    float sq = xv.x*xv.x + xv.y*xv.y + xv.z*xv.z + xv.w*xv.w;
    #pragma unroll
    for (int off = 32; off; off >>= 1) {
        s  += __shfl_down(s, off);
        sq += __shfl_down(sq, off);
    }
    if (lane == 0) { wsum[wv] = s; wsq[wv] = sq; }
    __syncthreads();
    const float ts = wsum[0] + wsum[1] + wsum[2] + wsum[3];
    const float tq = wsq[0] + wsq[1] + wsq[2] + wsq[3];
    const float mean = ts * (1.f / 1024.f);
    const float var  = tq * (1.f / 1024.f) - mean * mean;
    const float rstd = rsqrtf(var + 1e-5f);

    const float4 wv4 = ((const float4*)w)[tid];
    const float4 bv4 = ((const float4*)b)[tid];
    const float y0 = (xv.x - mean) * rstd * wv4.x + bv4.x;
    const float y1 = (xv.y - mean) * rstd * wv4.y + bv4.y;
    const float y2 = (xv.z - mean) * rstd * wv4.z + bv4.z;
    const float y3 = (xv.w - mean) * rstd * wv4.w + bv4.w;

    uint2 p;
    p.x = (unsigned)f2bf(y0) | ((unsigned)f2bf(y1) << 16);
    p.y = (unsigned)f2bf(y2) | ((unsigned)f2bf(y3) << 16);
    ((uint2*)(Ybf + (long)row * 1024))[tid] = p;

    if (DO_QK) {
        yrow[tid*4+0] = y0; yrow[tid*4+1] = y1;
        yrow[tid*4+2] = y2; yrow[tid*4+3] = y3;
        __syncthreads();
        #pragma unroll
        for (int i = 0; i < 4; ++i) {
            const int h = wv * 4 + i;
            const float* wqp = WQ + (long)h * 1024;
            const float* wkp = WK + (long)h * 1024;
            float dq = 0.f, dk = 0.f;
            #pragma unroll
            for (int j = 0; j < 16; ++j) {
                const float yv = yrow[lane + 64*j];
                dq = fmaf(yv, wqp[lane + 64*j], dq);
                dk = fmaf(yv, wkp[lane + 64*j], dk);
            }
            #pragma unroll
            for (int off = 32; off; off >>= 1) {
                dq += __shfl_down(dq, off);
                dk += __shfl_down(dk, off);
            }
            if (lane == 0) {
                const float aq = tanhf(dq) * (PI_F * 0.25f);
                const float ak = tanhf(dk) * (PI_F * 0.25f);
                float sv, cv;
                const long o = (long)h * 8192 + row;
                __sincosf(aq, &sv, &cv); cqA[o] = cv; sqA[o] = sv;
                __sincosf(ak, &sv, &cv); ckA[o] = cv; skA[o] = sv;
            }
        }
    }
}

// ---------------------------------------------------------------------------
// Fused cumsum scan + heads: one wave per (b, head).
// ---------------------------------------------------------------------------
__global__ __launch_bounds__(64)
void scan_kernel(const u16* __restrict__ V,
                 const float* __restrict__ cqA, const float* __restrict__ sqA,
                 const float* __restrict__ ckA, const float* __restrict__ skA,
                 u16* __restrict__ H)
{
    __shared__ u16 vt[64][64];
    __shared__ float lck[64], lsk[64], lrc[64], lrs[64];
    const int b = blockIdx.x >> 4;
    const int h = blockIdx.x & 15;
    const int lane = threadIdx.x;
    const long rowbase = (long)b * 2048;
    const long colbase = (long)h * 64;
    const long qbase = (long)h * 8192 + rowbase;

    float csum = 0.f, ssum = 0.f;
    float carry_c = 0.f, carry_s = 0.f;

    for (int ch = 0; ch < 32; ++ch) {
        const int t0 = ch * 64;
        __syncthreads();
        #pragma unroll
        for (int i = 0; i < 8; ++i) {
            const int tt = i * 8 + (lane >> 3);
            const int c0 = (lane & 7) * 8;
            *(u32x4*)&vt[tt][c0] =
                *(const u32x4*)(V + (rowbase + t0 + tt) * 1024 + colbase + c0);
        }
        {
            const float ck = ckA[qbase + t0 + lane];
            const float sk = skA[qbase + t0 + lane];
            const float cq = cqA[qbase + t0 + lane];
            const float sq = sqA[qbase + t0 + lane];
            float c = ck, sscan = sk;
            #pragma unroll
            for (int off = 1; off < 64; off <<= 1) {
                const float oc = __shfl_up(c, off);
                const float os = __shfl_up(sscan, off);
                if (lane >= off) { c += oc; sscan += os; }
            }
            const float cK = carry_c + c;
            const float sK = carry_s + sscan;
            carry_c += __shfl(c, 63);
            carry_s += __shfl(sscan, 63);
            const float denom = cq * cK + sq * sK + 1e-6f;
            lck[lane] = ck; lsk[lane] = sk;
            lrc[lane] = cq / denom; lrs[lane] = sq / denom;
        }
        __syncthreads();
        u16* outp = H + (rowbase + t0) * 1024 + colbase + lane;
        #pragma unroll 8
        for (int tt = 0; tt < 64; ++tt) {
            const float v = bf2f(vt[tt][lane]);
            csum = fmaf(lck[tt], v, csum);
            ssum = fmaf(lsk[tt], v, ssum);
            const float hv = lrc[tt] * csum + lrs[tt] * ssum;
            outp[(long)tt * 1024] = f2bf(hv);
        }
    }
}

// ---------------------------------------------------------------------------
// bf16 MFMA GEMM:  C[M][N] = A[M][K] * B^T  (Bt stored [N][K]).
// 128x128 tile, BK=32, 4 waves (2x2), m97 structure: global_load_lds width-16
// staging, 2 barriers per K-step, chunk-rotation swizzle (source-side) to
// kill the 8-way ds_read_b128 bank conflict.
// EPI: 0 = bf16 store; 1 = f32 store + res; 2 = bf16 gelu(acc+bias);
//      3 = f32 store + res + bias.
// ---------------------------------------------------------------------------
template<int EPI>
__global__ __launch_bounds__(256, 2)
void gemm_bt(const u16* __restrict__ A, const u16* __restrict__ B,
             void* __restrict__ Cout, const float* __restrict__ res,
             const float* __restrict__ bias, int M, int N, int K)
{
    __shared__ u16 As[128 * 32];
    __shared__ u16 Bs[128 * 32];
    const int tid  = threadIdx.x;
    const int lane = tid & 63;
    const int wave = tid >> 6;
    const int wr = wave >> 1;
    const int wc = wave & 1;
    const int brow = blockIdx.y * 128;
    const int bcol = blockIdx.x * 128;

    // staging: thread tid owns LDS row srow (and srow+64), dest chunk cdst.
    // LDS dest is lane-linear (tid*16B). Source chunk is inverse-rotated so
    // that physical chunk p at row r holds logical chunk (p - (r>>1))&3.
    const int srow = tid >> 2;
    const int cdst = tid & 3;
    const int csrc = (cdst - (srow >> 1)) & 3;
    const u16* Ag = A + (long)(brow + srow) * K + csrc * 8;
    const u16* Bg = B + (long)(bcol + srow) * K + csrc * 8;
    const u16* lA0 = &As[tid * 8];
    const u16* lA1 = &As[2048 + tid * 8];
    const u16* lB0 = &Bs[tid * 8];
    const u16* lB1 = &Bs[2048 + tid * 8];

    f32x4 acc[4][4];
    #pragma unroll
    for (int i = 0; i < 4; ++i)
        #pragma unroll
        for (int j = 0; j < 4; ++j) acc[i][j] = (f32x4){0.f, 0.f, 0.f, 0.f};

    const int rr = lane & 15;
    // read-side rotation: logical chunk = lane>>4; (r>>1)&3 == (rr>>1)&3
    // for all fragment rows (wr*64, wc*64, m*16 are multiples of 4 rows).
    const int physc = ((lane >> 4) + (rr >> 1)) & 3;
    const char* Ab = (const char*)As;
    const char* Bb = (const char*)Bs;
    const int aoff0 = (wr * 64 + rr) * 64 + physc * 16;
    const int boff0 = (wc * 64 + rr) * 64 + physc * 16;

    const int KT = K >> 5;
    for (int kt = 0; kt < KT; ++kt) {
        const long ko = (long)kt * 32;
        __syncthreads();                       // all waves done reading prev tile
        glds16(Ag + ko, lA0);
        glds16(Ag + ko + (long)64 * K, lA1);
        glds16(Bg + ko, lB0);
        glds16(Bg + ko + (long)64 * K, lB1);
        __syncthreads();                       // vmcnt(0) drain + barrier
        bfx8 af[4], bfr[4];
        #pragma unroll
        for (int m = 0; m < 4; ++m)
            af[m] = *(const bfx8*)(Ab + aoff0 + m * (16 * 64));
        #pragma unroll
        for (int n = 0; n < 4; ++n)
            bfr[n] = *(const bfx8*)(Bb + boff0 + n * (16 * 64));
        #pragma unroll
        for (int m = 0; m < 4; ++m)
            #pragma unroll
            for (int n = 0; n < 4; ++n)
                acc[m][n] = __builtin_amdgcn_mfma_f32_16x16x32_bf16(
                    af[m], bfr[n], acc[m][n], 0, 0, 0);
    }

    const int crow0 = brow + wr * 64 + (lane >> 4) * 4;
    const int ccol0 = bcol + wc * 64 + (lane & 15);
    #pragma unroll
    for (int m = 0; m < 4; ++m) {
        #pragma unroll
        for (int n = 0; n < 4; ++n) {
            const int col = ccol0 + n * 16;
            #pragma unroll
            for (int r = 0; r < 4; ++r) {
                const int row = crow0 + m * 16 + r;
                const long idx = (long)row * N + col;
                const float v = acc[m][n][r];
                if (EPI == 0) {
                    ((u16*)Cout)[idx] = f2bf(v);
                } else if (EPI == 1) {
                    ((float*)Cout)[idx] = v + res[idx];
                } else if (EPI == 2) {
                    const float hh = v + bias[col];
                    const float g = 0.5f * hh *
                        (1.f + tanhf(0.7978845608028654f * (hh + 0.044715f * hh * hh * hh)));
                    ((u16*)Cout)[idx] = f2bf(g);
                } else {
                    ((float*)Cout)[idx] = v + res[idx] + bias[col];
                }
            }
        }
    }
}

// ---------------------------------------------------------------------------
extern "C" void kernel_launch(void* const* d_in, const int* in_sizes, int n_in,
                              void* d_out, int out_size, void* d_ws, size_t ws_size,
                              hipStream_t stream)
{
    (void)in_sizes; (void)n_in; (void)out_size; (void)ws_size;
    const float* x    = (const float*)d_in[0];
    const float* WQ   = (const float*)d_in[1];
    const float* WK   = (const float*)d_in[2];
    const float* WV   = (const float*)d_in[3];
    const float* WO   = (const float*)d_in[4];
    const float* ln1w = (const float*)d_in[5];
    const float* ln1b = (const float*)d_in[6];
    const float* ln2w = (const float*)d_in[7];
    const float* ln2b = (const float*)d_in[8];
    const float* W1   = (const float*)d_in[9];
    const float* b1   = (const float*)d_in[10];
    const float* W2   = (const float*)d_in[11];
    const float* b2   = (const float*)d_in[12];
    float* out = (float*)d_out;

    char* ws = (char*)d_ws;
    u16*   Ybf  = (u16*)(ws + 0);                    // 16 MB (reused as y2)
    u16*   Vbf  = (u16*)(ws + 16777216);             // 16 MB
    u16*   Hbf  = (u16*)(ws + 33554432);             // 16 MB
    float* X2   = (float*)(ws + 50331648);           // 32 MB
    u16*   H1   = (u16*)(ws + 83886080);             // 64 MB
    u16*   WVT  = (u16*)(ws + 150994944);            //  2 MB
    u16*   WOT  = (u16*)(ws + 153092096);            //  2 MB
    u16*   W1T  = (u16*)(ws + 155189248);            //  8 MB
    u16*   W2T  = (u16*)(ws + 163577856);            //  8 MB
    float* CQ   = (float*)(ws + 171966464);
    float* SQ   = (float*)(ws + 172490752);
    float* CK   = (float*)(ws + 173015040);
    float* SK   = (float*)(ws + 173539328);

    // weight transposes/converts to Bt[n][k] bf16
    tconv_kernel<<<dim3(1, 16, 16), 256, 0, stream>>>(WV, WVT, 1024, 64, 1024L*64, 64L*1024);
    tconv_kernel<<<dim3(1, 1, 1024), 256, 0, stream>>>(WO, WOT, 64, 16, 1024L, 1024L);
    tconv_kernel<<<dim3(64, 16, 1), 256, 0, stream>>>(W1, W1T, 1024, 4096, 0L, 0L);
    tconv_kernel<<<dim3(16, 64, 1), 256, 0, stream>>>(W2, W2T, 4096, 1024, 0L, 0L);

    // LN1 + q/k rank-1 projections + tanh/cos/sin
    ln_kernel<true><<<8192, 256, 0, stream>>>(x, ln1w, ln1b, Ybf, WQ, WK, CQ, SQ, CK, SK);

    // V = y @ Wv
    gemm_bt<0><<<dim3(8, 64), 256, 0, stream>>>(Ybf, WVT, Vbf, nullptr, nullptr, 8192, 1024, 1024);

    // cumsum scan + heads
    scan_kernel<<<64, 64, 0, stream>>>(Vbf, CQ, SQ, CK, SK, Hbf);

    // x2 = x + heads @ Wo
    gemm_bt<1><<<dim3(8, 64), 256, 0, stream>>>(Hbf, WOT, X2, x, nullptr, 8192, 1024, 1024);

    // LN2 (y2 reuses Ybf)
    ln_kernel<false><<<8192, 256, 0, stream>>>(X2, ln2w, ln2b, Ybf,
                                               nullptr, nullptr, nullptr, nullptr, nullptr, nullptr);

    // h1 = gelu(y2 @ W1 + b1)
    gemm_bt<2><<<dim3(32, 64), 256, 0, stream>>>(Ybf, W1T, H1, nullptr, b1, 8192, 4096, 1024);

    // out = x2 + h1 @ W2 + b2
    gemm_bt<3><<<dim3(8, 64), 256, 0, stream>>>(H1, W2T, out, X2, b2, 8192, 1024, 4096);
}

// Round 3
// 522.727 us; speedup vs baseline: 1.0728x; 1.0702x over previous
//
#include <hip/hip_runtime.h>
#include <hip/hip_bf16.h>
#include <stdint.h>

typedef unsigned short u16;
typedef __attribute__((ext_vector_type(4))) unsigned int u32x4;
typedef __attribute__((ext_vector_type(8))) __bf16 bfx8;
typedef __attribute__((ext_vector_type(4))) float f32x4;

#define PI_F 3.14159265358979323846f

__device__ __forceinline__ float bf2f(u16 u) {
    unsigned v = ((unsigned)u) << 16; float f; __builtin_memcpy(&f, &v, 4); return f;
}
__device__ __forceinline__ u16 f2bf(float f) {
    unsigned u; __builtin_memcpy(&u, &f, 4);
    unsigned r = (u + 0x7fffu + ((u >> 16) & 1u)) >> 16; return (u16)r;
}

// global -> LDS direct DMA, 16B per lane. LDS dest must be lane-linear.
__device__ __forceinline__ void glds16(const u16* g, const u16* l) {
    __builtin_amdgcn_global_load_lds(
        (const __attribute__((address_space(1))) unsigned int*)(unsigned long long)g,
        (__attribute__((address_space(3))) unsigned int*)(unsigned int)(unsigned long long)l,
        16, 0, 0);
}

// ---------------------------------------------------------------------------
// Generic tiled transpose + f32->bf16 convert:  out[c][r] = in[r][c], batched.
// ---------------------------------------------------------------------------
__global__ __launch_bounds__(256)
void tconv_kernel(const float* __restrict__ in, u16* __restrict__ out,
                  int R, int C, long inBatch, long outBatch)
{
    __shared__ float tile[64][65];
    const int tx = threadIdx.x & 63;
    const int ty = threadIdx.x >> 6;
    const int bc = blockIdx.x * 64;
    const int br = blockIdx.y * 64;
    const float* ip = in + (long)blockIdx.z * inBatch;
    u16* op = out + (long)blockIdx.z * outBatch;

    #pragma unroll
    for (int rr = ty; rr < 64; rr += 4) {
        int r = br + rr, c = bc + tx;
        tile[rr][tx] = (r < R && c < C) ? ip[(long)r * C + c] : 0.f;
    }
    __syncthreads();
    #pragma unroll
    for (int rr = ty; rr < 64; rr += 4) {
        int oc = bc + rr;
        int orr = br + tx;
        if (oc < C && orr < R)
            op[(long)oc * R + orr] = f2bf(tile[tx][rr]);
    }
}

// ---------------------------------------------------------------------------
// LayerNorm (+ optional rank-1 q/k projections + tanh/cos/sin).
// ---------------------------------------------------------------------------
template<bool DO_QK>
__global__ __launch_bounds__(256)
void ln_kernel(const float* __restrict__ X, const float* __restrict__ w,
               const float* __restrict__ b, u16* __restrict__ Ybf,
               const float* __restrict__ WQ, const float* __restrict__ WK,
               float* __restrict__ cqA, float* __restrict__ sqA,
               float* __restrict__ ckA, float* __restrict__ skA)
{
    __shared__ float yrow[1024];
    __shared__ float wsum[4], wsq[4];
    const int row = blockIdx.x;
    const int tid = threadIdx.x;
    const int lane = tid & 63;
    const int wv = tid >> 6;

    const float4 xv = ((const float4*)(X + (long)row * 1024))[tid];
    float s  = xv.x + xv.y + xv.z + xv.w;
    float sq = xv.x*xv.x + xv.y*xv.y + xv.z*xv.z + xv.w*xv.w;
    #pragma unroll
    for (int off = 32; off; off >>= 1) {
        s  += __shfl_down(s, off);
        sq += __shfl_down(sq, off);
    }
    if (lane == 0) { wsum[wv] = s; wsq[wv] = sq; }
    __syncthreads();
    const float ts = wsum[0] + wsum[1] + wsum[2] + wsum[3];
    const float tq = wsq[0] + wsq[1] + wsq[2] + wsq[3];
    const float mean = ts * (1.f / 1024.f);
    const float var  = tq * (1.f / 1024.f) - mean * mean;
    const float rstd = rsqrtf(var + 1e-5f);

    const float4 wv4 = ((const float4*)w)[tid];
    const float4 bv4 = ((const float4*)b)[tid];
    const float y0 = (xv.x - mean) * rstd * wv4.x + bv4.x;
    const float y1 = (xv.y - mean) * rstd * wv4.y + bv4.y;
    const float y2 = (xv.z - mean) * rstd * wv4.z + bv4.z;
    const float y3 = (xv.w - mean) * rstd * wv4.w + bv4.w;

    uint2 p;
    p.x = (unsigned)f2bf(y0) | ((unsigned)f2bf(y1) << 16);
    p.y = (unsigned)f2bf(y2) | ((unsigned)f2bf(y3) << 16);
    ((uint2*)(Ybf + (long)row * 1024))[tid] = p;

    if (DO_QK) {
        yrow[tid*4+0] = y0; yrow[tid*4+1] = y1;
        yrow[tid*4+2] = y2; yrow[tid*4+3] = y3;
        __syncthreads();
        #pragma unroll
        for (int i = 0; i < 4; ++i) {
            const int h = wv * 4 + i;
            const float* wqp = WQ + (long)h * 1024;
            const float* wkp = WK + (long)h * 1024;
            float dq = 0.f, dk = 0.f;
            #pragma unroll
            for (int j = 0; j < 16; ++j) {
                const float yv = yrow[lane + 64*j];
                dq = fmaf(yv, wqp[lane + 64*j], dq);
                dk = fmaf(yv, wkp[lane + 64*j], dk);
            }
            #pragma unroll
            for (int off = 32; off; off >>= 1) {
                dq += __shfl_down(dq, off);
                dk += __shfl_down(dk, off);
            }
            if (lane == 0) {
                const float aq = tanhf(dq) * (PI_F * 0.25f);
                const float ak = tanhf(dk) * (PI_F * 0.25f);
                float sv, cv;
                const long o = (long)h * 8192 + row;
                __sincosf(aq, &sv, &cv); cqA[o] = cv; sqA[o] = sv;
                __sincosf(ak, &sv, &cv); ckA[o] = cv; skA[o] = sv;
            }
        }
    }
}

// ---------------------------------------------------------------------------
// Fused cumsum scan + heads: one wave per (b, head).
// ---------------------------------------------------------------------------
__global__ __launch_bounds__(64)
void scan_kernel(const u16* __restrict__ V,
                 const float* __restrict__ cqA, const float* __restrict__ sqA,
                 const float* __restrict__ ckA, const float* __restrict__ skA,
                 u16* __restrict__ H)
{
    __shared__ u16 vt[64][64];
    __shared__ float lck[64], lsk[64], lrc[64], lrs[64];
    const int b = blockIdx.x >> 4;
    const int h = blockIdx.x & 15;
    const int lane = threadIdx.x;
    const long rowbase = (long)b * 2048;
    const long colbase = (long)h * 64;
    const long qbase = (long)h * 8192 + rowbase;

    float csum = 0.f, ssum = 0.f;
    float carry_c = 0.f, carry_s = 0.f;

    for (int ch = 0; ch < 32; ++ch) {
        const int t0 = ch * 64;
        __syncthreads();
        #pragma unroll
        for (int i = 0; i < 8; ++i) {
            const int tt = i * 8 + (lane >> 3);
            const int c0 = (lane & 7) * 8;
            *(u32x4*)&vt[tt][c0] =
                *(const u32x4*)(V + (rowbase + t0 + tt) * 1024 + colbase + c0);
        }
        {
            const float ck = ckA[qbase + t0 + lane];
            const float sk = skA[qbase + t0 + lane];
            const float cq = cqA[qbase + t0 + lane];
            const float sq = sqA[qbase + t0 + lane];
            float c = ck, sscan = sk;
            #pragma unroll
            for (int off = 1; off < 64; off <<= 1) {
                const float oc = __shfl_up(c, off);
                const float os = __shfl_up(sscan, off);
                if (lane >= off) { c += oc; sscan += os; }
            }
            const float cK = carry_c + c;
            const float sK = carry_s + sscan;
            carry_c += __shfl(c, 63);
            carry_s += __shfl(sscan, 63);
            const float denom = cq * cK + sq * sK + 1e-6f;
            lck[lane] = ck; lsk[lane] = sk;
            lrc[lane] = cq / denom; lrs[lane] = sq / denom;
        }
        __syncthreads();
        u16* outp = H + (rowbase + t0) * 1024 + colbase + lane;
        #pragma unroll 8
        for (int tt = 0; tt < 64; ++tt) {
            const float v = bf2f(vt[tt][lane]);
            csum = fmaf(lck[tt], v, csum);
            ssum = fmaf(lsk[tt], v, ssum);
            const float hv = lrc[tt] * csum + lrs[tt] * ssum;
            outp[(long)tt * 1024] = f2bf(hv);
        }
    }
}

// ---------------------------------------------------------------------------
// 256-row deep-pipelined bf16 MFMA GEMM:  C[M][N] = A[M][K] * B^T (Bt [N][K]).
// BM=256, BN=256 or 128, BK=32, 8 waves (2Mx4N), 512 threads.
// 4 LDS buffers, prefetch 3 K-tiles ahead via global_load_lds, counted
// s_waitcnt vmcnt(2*GPT) at tile boundary only (never 0 in main loop).
// 2 phases/K-tile, raw s_barrier, setprio(1) around MFMA clusters.
// Chunk-rotation LDS swizzle (source-side, proven 0-conflict in round 2).
// XCD swizzle colocates each 256-row panel's column-blocks on one XCD.
// EPI: 0 = bf16 store; 1 = f32 store+res; 2 = bf16 gelu(acc+bias);
//      3 = f32 store+res+bias.
// ---------------------------------------------------------------------------
template<int EPI, int BN>
__global__ __launch_bounds__(512, 2)
void gemm256(const u16* __restrict__ A, const u16* __restrict__ B,
             void* __restrict__ Cout, const float* __restrict__ res,
             const float* __restrict__ bias, int M, int N, int K, int nx)
{
    constexpr int NREP = BN / 64;               // 4 or 2
    constexpr int GPT  = (BN == 256) ? 4 : 3;   // glds issues per K-tile
    __shared__ u16 As[4 * 256 * 32];
    __shared__ u16 Bs[4 * BN * 32];

    const int tid  = threadIdx.x;
    const int lane = tid & 63;
    const int wave = tid >> 6;
    const int wr = wave >> 2;          // 0..1
    const int wc = wave & 3;           // 0..3

    // XCD-colocating swizzle: all column-blocks of a row-panel on one XCD.
    const int L = blockIdx.x;
    const int xcd = L & 7;
    const int q = L >> 3;
    const int bx = q % nx;
    const int by = (q / nx) * 8 + xcd;
    const int brow = by * 256;
    const int bcol = bx * BN;

    // staging map: thread t -> (srow = t>>2, chunk cd = t&3), source chunk
    // inverse-rotated so phys chunk p of row r holds logical chunk (p-(r>>1))&3.
    const int srow = tid >> 2;          // 0..127
    const int cd = tid & 3;
    const int csrc = (cd - (srow >> 1)) & 3;
    const u16* AgB = A + (long)(brow + srow) * K + csrc * 8;
    const u16* BgB = B + (long)(bcol + srow) * K + csrc * 8;
    const long rowK128 = (long)128 * K;

    // fragment-read offsets (rotation applied on read side)
    const int rr = lane & 15;
    const int physc = ((lane >> 4) + (rr >> 1)) & 3;
    const int aro = (wr * 128 + rr) * 64 + physc * 16;         // bytes
    const int bro = (wc * (BN / 4) + rr) * 64 + physc * 16;    // bytes

    f32x4 acc[8][NREP];
    #pragma unroll
    for (int m = 0; m < 8; ++m)
        #pragma unroll
        for (int n = 0; n < NREP; ++n) acc[m][n] = (f32x4){0.f, 0.f, 0.f, 0.f};

    const int NT = K >> 5;
    const char* Ab = (const char*)As;
    const char* Bb = (const char*)Bs;

    // prologue: stage tiles 0,1,2 into bufs 0,1,2
    #pragma unroll
    for (int t = 0; t < 3; ++t) {
        const int kof = t * 32;
        glds16(AgB + kof,            &As[t * 8192 + tid * 8]);
        glds16(AgB + kof + rowK128,  &As[t * 8192 + 4096 + tid * 8]);
        glds16(BgB + kof,            &Bs[t * (BN * 32) + tid * 8]);
        if constexpr (BN == 256)
            glds16(BgB + kof + rowK128, &Bs[t * 8192 + 4096 + tid * 8]);
    }
    if constexpr (GPT == 4) asm volatile("s_waitcnt vmcnt(8)" ::: "memory");
    else                    asm volatile("s_waitcnt vmcnt(6)" ::: "memory");
    __builtin_amdgcn_s_barrier();

    for (int kt = 0; kt < NT; ++kt) {
        const int cur = kt & 3;
        const int pf  = (kt + 3) & 3;
        const int kof = ((kt + 3) < NT) ? (kt + 3) * 32 : 0;   // clamp: data unused
        const char* Abuf = Ab + cur * 16384;
        const char* Bbuf = Bb + cur * (BN * 64);

        bfx8 af[8], bf[NREP];
        // ---- phase 0: all A-frags + first-half B-frags; stage A of kt+3
        #pragma unroll
        for (int m = 0; m < 8; ++m)
            af[m] = *(const bfx8*)(Abuf + aro + m * 1024);
        #pragma unroll
        for (int n = 0; n < NREP / 2; ++n)
            bf[n] = *(const bfx8*)(Bbuf + bro + n * 1024);
        glds16(AgB + kof,           &As[pf * 8192 + tid * 8]);
        glds16(AgB + kof + rowK128, &As[pf * 8192 + 4096 + tid * 8]);
        __builtin_amdgcn_s_barrier();
        asm volatile("s_waitcnt lgkmcnt(0)" ::: "memory");
        __builtin_amdgcn_sched_barrier(0);
        __builtin_amdgcn_s_setprio(1);
        #pragma unroll
        for (int m = 0; m < 8; ++m)
            #pragma unroll
            for (int n = 0; n < NREP / 2; ++n)
                acc[m][n] = __builtin_amdgcn_mfma_f32_16x16x32_bf16(
                    af[m], bf[n], acc[m][n], 0, 0, 0);
        __builtin_amdgcn_s_setprio(0);
        __builtin_amdgcn_sched_barrier(0);
        __builtin_amdgcn_s_barrier();

        // ---- phase 1: second-half B-frags; stage B of kt+3
        #pragma unroll
        for (int n = NREP / 2; n < NREP; ++n)
            bf[n] = *(const bfx8*)(Bbuf + bro + n * 1024);
        glds16(BgB + kof, &Bs[pf * (BN * 32) + tid * 8]);
        if constexpr (BN == 256)
            glds16(BgB + kof + rowK128, &Bs[pf * 8192 + 4096 + tid * 8]);
        __builtin_amdgcn_s_barrier();
        asm volatile("s_waitcnt lgkmcnt(0)" ::: "memory");
        __builtin_amdgcn_sched_barrier(0);
        __builtin_amdgcn_s_setprio(1);
        #pragma unroll
        for (int m = 0; m < 8; ++m)
            #pragma unroll
            for (int n = NREP / 2; n < NREP; ++n)
                acc[m][n] = __builtin_amdgcn_mfma_f32_16x16x32_bf16(
                    af[m], bf[n], acc[m][n], 0, 0, 0);
        __builtin_amdgcn_s_setprio(0);
        __builtin_amdgcn_sched_barrier(0);
        // counted boundary wait: tiles kt+2, kt+3 stay in flight
        if constexpr (GPT == 4) asm volatile("s_waitcnt vmcnt(8)" ::: "memory");
        else                    asm volatile("s_waitcnt vmcnt(6)" ::: "memory");
        __builtin_amdgcn_s_barrier();
    }

    // epilogue
    const int crow0 = brow + wr * 128 + (lane >> 4) * 4;
    const int ccol0 = bcol + wc * (BN / 4) + rr;
    #pragma unroll
    for (int m = 0; m < 8; ++m) {
        #pragma unroll
        for (int n = 0; n < NREP; ++n) {
            const int col = ccol0 + n * 16;
            #pragma unroll
            for (int r = 0; r < 4; ++r) {
                const int row = crow0 + m * 16 + r;
                const long idx = (long)row * N + col;
                const float v = acc[m][n][r];
                if (EPI == 0) {
                    ((u16*)Cout)[idx] = f2bf(v);
                } else if (EPI == 1) {
                    ((float*)Cout)[idx] = v + res[idx];
                } else if (EPI == 2) {
                    const float hh = v + bias[col];
                    const float z = 0.7978845608028654f * (hh + 0.044715f * hh * hh * hh);
                    const float e = __expf(2.f * z);
                    const float th = 1.f - 2.f / (e + 1.f);   // tanh(z), saturating
                    ((u16*)Cout)[idx] = f2bf(0.5f * hh * (1.f + th));
                } else {
                    ((float*)Cout)[idx] = v + res[idx] + bias[col];
                }
            }
        }
    }
}

// ---------------------------------------------------------------------------
extern "C" void kernel_launch(void* const* d_in, const int* in_sizes, int n_in,
                              void* d_out, int out_size, void* d_ws, size_t ws_size,
                              hipStream_t stream)
{
    (void)in_sizes; (void)n_in; (void)out_size; (void)ws_size;
    const float* x    = (const float*)d_in[0];
    const float* WQ   = (const float*)d_in[1];
    const float* WK   = (const float*)d_in[2];
    const float* WV   = (const float*)d_in[3];
    const float* WO   = (const float*)d_in[4];
    const float* ln1w = (const float*)d_in[5];
    const float* ln1b = (const float*)d_in[6];
    const float* ln2w = (const float*)d_in[7];
    const float* ln2b = (const float*)d_in[8];
    const float* W1   = (const float*)d_in[9];
    const float* b1   = (const float*)d_in[10];
    const float* W2   = (const float*)d_in[11];
    const float* b2   = (const float*)d_in[12];
    float* out = (float*)d_out;

    char* ws = (char*)d_ws;
    u16*   Ybf  = (u16*)(ws + 0);                    // 16 MB (reused as y2)
    u16*   Vbf  = (u16*)(ws + 16777216);             // 16 MB
    u16*   Hbf  = (u16*)(ws + 33554432);             // 16 MB
    float* X2   = (float*)(ws + 50331648);           // 32 MB
    u16*   H1   = (u16*)(ws + 83886080);             // 64 MB
    u16*   WVT  = (u16*)(ws + 150994944);            //  2 MB
    u16*   WOT  = (u16*)(ws + 153092096);            //  2 MB
    u16*   W1T  = (u16*)(ws + 155189248);            //  8 MB
    u16*   W2T  = (u16*)(ws + 163577856);            //  8 MB
    float* CQ   = (float*)(ws + 171966464);
    float* SQ   = (float*)(ws + 172490752);
    float* CK   = (float*)(ws + 173015040);
    float* SK   = (float*)(ws + 173539328);

    // weight transposes/converts to Bt[n][k] bf16
    tconv_kernel<<<dim3(1, 16, 16), 256, 0, stream>>>(WV, WVT, 1024, 64, 1024L*64, 64L*1024);
    tconv_kernel<<<dim3(1, 1, 1024), 256, 0, stream>>>(WO, WOT, 64, 16, 1024L, 1024L);
    tconv_kernel<<<dim3(64, 16, 1), 256, 0, stream>>>(W1, W1T, 1024, 4096, 0L, 0L);
    tconv_kernel<<<dim3(16, 64, 1), 256, 0, stream>>>(W2, W2T, 4096, 1024, 0L, 0L);

    // LN1 + q/k rank-1 projections + tanh/cos/sin
    ln_kernel<true><<<8192, 256, 0, stream>>>(x, ln1w, ln1b, Ybf, WQ, WK, CQ, SQ, CK, SK);

    // V = y @ Wv   (8192x1024x1024)
    gemm256<0, 128><<<256, 512, 0, stream>>>(Ybf, WVT, Vbf, nullptr, nullptr, 8192, 1024, 1024, 8);

    // cumsum scan + heads
    scan_kernel<<<64, 64, 0, stream>>>(Vbf, CQ, SQ, CK, SK, Hbf);

    // x2 = x + heads @ Wo   (8192x1024x1024)
    gemm256<1, 128><<<256, 512, 0, stream>>>(Hbf, WOT, X2, x, nullptr, 8192, 1024, 1024, 8);

    // LN2 (y2 reuses Ybf)
    ln_kernel<false><<<8192, 256, 0, stream>>>(X2, ln2w, ln2b, Ybf,
                                               nullptr, nullptr, nullptr, nullptr, nullptr, nullptr);

    // h1 = gelu(y2 @ W1 + b1)  (8192x4096x1024)
    gemm256<2, 256><<<512, 512, 0, stream>>>(Ybf, W1T, H1, nullptr, b1, 8192, 4096, 1024, 16);

    // out = x2 + h1 @ W2 + b2  (8192x1024x4096)
    gemm256<3, 128><<<256, 512, 0, stream>>>(H1, W2T, out, X2, b2, 8192, 1024, 4096, 8);
}